// Round 7
// baseline (97.727 us; speedup 1.0000x reference)
//
#include <hip/hip_runtime.h>

#define NB 8
#define TE 256
#define TD 256
#define ED 512
#define DU 256

// EpeT2 layout: [b][uq=u/4][t][ui=u%4]  (64 x 256 x 4 floats per b = 65536)
// -> score reads one float4 (u-quad) per lane: 16B/lane, 1KB/wave.

// K1: proj+exp, 32x64 tiles, 512 threads (8 waves): K-split. Lower 256
// threads (h=0) accumulate K-half 0, upper (h=1) K-half 1; partials
// combined via LDS before epilogue. 2 blocks/CU x 8 waves = 4 waves/SIMD.
__global__ __launch_bounds__(512) void proj_exp_kernel(
    const float* __restrict__ enc, const float* __restrict__ dec,
    const float* __restrict__ W1, const float* __restrict__ b1,
    const float* __restrict__ W2, const float* __restrict__ b2,
    float* __restrict__ Epd, float* __restrict__ EpeT2)
{
  __shared__ __align__(16) float As[2][32][34];
  __shared__ __align__(16) float Bs[2][32][64];
  __shared__ __align__(16) float comb[8][256];
  const int blk = blockIdx.x;
  const bool is_pe = blk < 256;
  const int sub = blk & 255;
  const int K = is_pe ? ED : DU;
  const int NTh = K >> 6;  // K-tiles per half (pe: 8, pd: 4)
  const float* __restrict__ A = is_pe ? enc : dec;
  const float* __restrict__ W = is_pe ? W1 : W2;
  const float* __restrict__ bias = is_pe ? b1 : b2;
  const int mt = sub >> 2, nt = sub & 3;
  const int m0 = mt * 32, n0 = nt * 64;
  const int tid = threadIdx.x;
  const int t = tid & 255;  // index within half
  const int h = tid >> 8;   // K-half
  const int k0base = h * (K >> 1);
  const int tx = t & 15, ty = t >> 4;
  const int at = t >> 3, ka = (t & 7) << 2;   // A: row, k-offset
  const int kb = t >> 4, jb = (t & 15) << 2;  // W: k-row, col-offset

  const float* __restrict__ Ap = A + (size_t)(m0 + at) * K + k0base + ka;
  const float* __restrict__ Wp = W + (size_t)(k0base + kb) * DU + n0 + jb;

  float acc[2][4] = {};
  float4 aV, wV0, wV1;

  auto loadr = [&](int k0) {
    aV = *(const float4*)(Ap + k0);
    wV0 = *(const float4*)(Wp + (size_t)k0 * DU);
    wV1 = *(const float4*)(Wp + (size_t)(k0 + 16) * DU);
  };

  loadr(0);
  for (int kt = 0; kt < NTh; ++kt) {
    As[h][ka + 0][at] = aV.x;
    As[h][ka + 1][at] = aV.y;
    As[h][ka + 2][at] = aV.z;
    As[h][ka + 3][at] = aV.w;
    *(float4*)&Bs[h][kb][jb] = wV0;
    *(float4*)&Bs[h][kb + 16][jb] = wV1;
    __syncthreads();
    if (kt + 1 < NTh) loadr((kt + 1) << 5);
#pragma unroll
    for (int kk = 0; kk < 32; ++kk) {
      const float2 a2 = *(const float2*)&As[h][kk][ty * 2];
      const float4 w4 = *(const float4*)&Bs[h][kk][tx * 4];
      acc[0][0] = fmaf(a2.x, w4.x, acc[0][0]);
      acc[0][1] = fmaf(a2.x, w4.y, acc[0][1]);
      acc[0][2] = fmaf(a2.x, w4.z, acc[0][2]);
      acc[0][3] = fmaf(a2.x, w4.w, acc[0][3]);
      acc[1][0] = fmaf(a2.y, w4.x, acc[1][0]);
      acc[1][1] = fmaf(a2.y, w4.y, acc[1][1]);
      acc[1][2] = fmaf(a2.y, w4.z, acc[1][2]);
      acc[1][3] = fmaf(a2.y, w4.w, acc[1][3]);
    }
    __syncthreads();
  }

  // ---- combine K-halves ----
  if (h == 1) {
#pragma unroll
    for (int r = 0; r < 2; ++r)
#pragma unroll
      for (int j = 0; j < 4; ++j) comb[r * 4 + j][t] = acc[r][j];
  }
  __syncthreads();
  if (h == 0) {
#pragma unroll
    for (int r = 0; r < 2; ++r)
#pragma unroll
      for (int j = 0; j < 4; ++j) acc[r][j] += comb[r * 4 + j][t];

    const float4 bv4 = *(const float4*)(bias + n0 + tx * 4);
    const float bvv[4] = {bv4.x, bv4.y, bv4.z, bv4.w};
    if (is_pe) {
      // u-quad interleaved write: thread owns uq = n0/4+tx, t = t0+ty*2(+r)
      const int b = m0 >> 8, t0 = m0 & 255;
      const int uqg = (b << 6) + (n0 >> 2) + tx;
      const int tg = t0 + ty * 2;
      float* dst = EpeT2 + ((size_t)uqg << 10) + (tg << 2);
      float4 o0, o1;
      o0.x = __expf(2.0f * (acc[0][0] + bvv[0]));
      o0.y = __expf(2.0f * (acc[0][1] + bvv[1]));
      o0.z = __expf(2.0f * (acc[0][2] + bvv[2]));
      o0.w = __expf(2.0f * (acc[0][3] + bvv[3]));
      o1.x = __expf(2.0f * (acc[1][0] + bvv[0]));
      o1.y = __expf(2.0f * (acc[1][1] + bvv[1]));
      o1.z = __expf(2.0f * (acc[1][2] + bvv[2]));
      o1.w = __expf(2.0f * (acc[1][3] + bvv[3]));
      *(float4*)dst = o0;
      *(float4*)(dst + 4) = o1;
    } else {
#pragma unroll
      for (int r = 0; r < 2; ++r) {
        const int m = m0 + ty * 2 + r;  // global dec row (b*256+s)
        float4 o;
        o.x = __expf(2.0f * (acc[r][0] + bvv[0]));
        o.y = __expf(2.0f * (acc[r][1] + bvv[1]));
        o.z = __expf(2.0f * (acc[r][2] + bvv[2]));
        o.w = __expf(2.0f * (acc[r][3] + bvv[3]));
        *(float4*)(Epd + ((size_t)m << 8) + n0 + tx * 4) = o;
      }
    }
  }
}

// K23: fused score+softmax+context, 1024 threads (16 waves), grid 512 =
// (b, s-quad) -> 2 blocks/CU x 16 waves = 8 waves/SIMD (2x R5 occupancy).
// XCD swizzle keeps each batch's 64 blocks on one XCD.
// Phase 1: u-QUARTER split (hq = tid>>8, 16 q-iters each) over LDS-staged
// Epd rows + Vw (broadcast ds_read) and per-lane EpeT2 float4 loads
// (prefetched one iter ahead). Partials combined via 12KB LDS.
// Softmax: no-max variant (|score| <= 2*sum|Vw| ~ 26, exp fp32-safe;
// validated in R6) on the low 4 waves.
// Phase 2: t-half split (h2 = tid>>9); thread owns ctx col c=tid&511 x 4
// rows over its t-half; partials combined via 8KB LDS. enc read once/block.
__global__ __launch_bounds__(1024, 8) void score_ctx_kernel(
    const float* __restrict__ Epd, const float* __restrict__ EpeT2,
    const float* __restrict__ Vw, const float* __restrict__ enc,
    float* __restrict__ attn, float* __restrict__ ctx)
{
  __shared__ __align__(16) float eps[4 * 256];     // Epd rows (4KB)
  __shared__ __align__(16) float vws[256];         // Vw (1KB)
  __shared__ __align__(16) float comb[3][4][256];  // u-quarter partials (12KB)
  __shared__ __align__(16) float att[4][256];      // probs (4KB)
  __shared__ __align__(16) float ctx2[4][512];     // t-half partials (8KB)
  __shared__ float reds[4][4];

  const int blk0 = blockIdx.x;
  const int blk = ((blk0 & 7) << 6) | (blk0 >> 3);  // T1 XCD swizzle
  const int b = blk >> 6;
  const int s0 = (blk & 63) << 2;
  const int tid = threadIdx.x;
  const int t = tid & 255;   // enc position
  const int hq = tid >> 8;   // u-quarter (0..3)

  // ---- stage Epd 4 rows (contiguous 4KB) + Vw (1KB) into LDS ----
  if (hq == 0) {
    ((float4*)eps)[t] =
        ((const float4*)(Epd + (((size_t)((b << 8) + s0)) << 8)))[t];
  } else if (hq == 1 && t < 64) {
    ((float4*)vws)[t] = ((const float4*)Vw)[t];
  }
  __syncthreads();

  // ---- Phase 1: score partials for u-quarter hq (q = hq*16 .. +15) ----
  const int qb = hq << 4;
  const float* __restrict__ ep =
      EpeT2 + ((size_t)b << 16) + ((size_t)qb << 10) + (t << 2);

  float a0 = 0.f, a1 = 0.f, a2 = 0.f, a3 = 0.f;
  float4 g = *(const float4*)ep;
#pragma unroll 4
  for (int q = 0; q < 16; ++q) {
    float4 gn;
    if (q + 1 < 16) gn = *(const float4*)(ep + ((size_t)(q + 1) << 10));
    const int u4 = (qb + q) << 2;
    const float4 vw = *(const float4*)&vws[u4];
    const float4 e0 = *(const float4*)&eps[u4];
    const float4 e1 = *(const float4*)&eps[256 + u4];
    const float4 e2 = *(const float4*)&eps[512 + u4];
    const float4 e3 = *(const float4*)&eps[768 + u4];
    a0 = fmaf(vw.x, __builtin_amdgcn_rcpf(fmaf(e0.x, g.x, 1.0f)), a0);
    a1 = fmaf(vw.x, __builtin_amdgcn_rcpf(fmaf(e1.x, g.x, 1.0f)), a1);
    a2 = fmaf(vw.x, __builtin_amdgcn_rcpf(fmaf(e2.x, g.x, 1.0f)), a2);
    a3 = fmaf(vw.x, __builtin_amdgcn_rcpf(fmaf(e3.x, g.x, 1.0f)), a3);
    a0 = fmaf(vw.y, __builtin_amdgcn_rcpf(fmaf(e0.y, g.y, 1.0f)), a0);
    a1 = fmaf(vw.y, __builtin_amdgcn_rcpf(fmaf(e1.y, g.y, 1.0f)), a1);
    a2 = fmaf(vw.y, __builtin_amdgcn_rcpf(fmaf(e2.y, g.y, 1.0f)), a2);
    a3 = fmaf(vw.y, __builtin_amdgcn_rcpf(fmaf(e3.y, g.y, 1.0f)), a3);
    a0 = fmaf(vw.z, __builtin_amdgcn_rcpf(fmaf(e0.z, g.z, 1.0f)), a0);
    a1 = fmaf(vw.z, __builtin_amdgcn_rcpf(fmaf(e1.z, g.z, 1.0f)), a1);
    a2 = fmaf(vw.z, __builtin_amdgcn_rcpf(fmaf(e2.z, g.z, 1.0f)), a2);
    a3 = fmaf(vw.z, __builtin_amdgcn_rcpf(fmaf(e3.z, g.z, 1.0f)), a3);
    a0 = fmaf(vw.w, __builtin_amdgcn_rcpf(fmaf(e0.w, g.w, 1.0f)), a0);
    a1 = fmaf(vw.w, __builtin_amdgcn_rcpf(fmaf(e1.w, g.w, 1.0f)), a1);
    a2 = fmaf(vw.w, __builtin_amdgcn_rcpf(fmaf(e2.w, g.w, 1.0f)), a2);
    a3 = fmaf(vw.w, __builtin_amdgcn_rcpf(fmaf(e3.w, g.w, 1.0f)), a3);
    g = gn;
  }

  if (hq != 0) {
    comb[hq - 1][0][t] = a0;
    comb[hq - 1][1][t] = a1;
    comb[hq - 1][2][t] = a2;
    comb[hq - 1][3][t] = a3;
  }
  __syncthreads();

  // ---- combine + no-max softmax on lowest 4 waves ----
  const int wid = tid >> 6, lane = tid & 63;
  float e[4];
  if (hq == 0) {
    float vv[4];
    vv[0] = a0 + comb[0][0][t] + comb[1][0][t] + comb[2][0][t];
    vv[1] = a1 + comb[0][1][t] + comb[1][1][t] + comb[2][1][t];
    vv[2] = a2 + comb[0][2][t] + comb[1][2][t] + comb[2][2][t];
    vv[3] = a3 + comb[0][3][t] + comb[1][3][t] + comb[2][3][t];
#pragma unroll
    for (int r = 0; r < 4; ++r) {
      e[r] = __expf(-2.f * vv[r]);
      float s = e[r];
#pragma unroll
      for (int off = 32; off; off >>= 1) s += __shfl_xor(s, off);
      if (lane == 0) reds[r][wid] = s;
    }
  }
  __syncthreads();
  if (hq == 0) {
#pragma unroll
    for (int r = 0; r < 4; ++r) {
      const float s = (reds[r][0] + reds[r][1]) + (reds[r][2] + reds[r][3]);
      const float p = e[r] * __builtin_amdgcn_rcpf(s);
      attn[(((size_t)((b << 8) + s0 + r)) << 8) + t] = p;
      att[r][t] = p;
    }
  }
  __syncthreads();

  // ---- Phase 2: ctx col c, 4 rows, t-half h2. enc read once per block. ----
  const int c = tid & 511;
  const int h2 = tid >> 9;
  const int tb = h2 << 7;
  const float* __restrict__ encb = enc + ((size_t)b << 17) + c;
  float acc0 = 0.f, acc1 = 0.f, acc2 = 0.f, acc3 = 0.f;
#pragma unroll 2
  for (int t0 = tb; t0 < tb + 128; t0 += 4) {
    const float4 p0 = *(const float4*)&att[0][t0];
    const float4 p1 = *(const float4*)&att[1][t0];
    const float4 p2 = *(const float4*)&att[2][t0];
    const float4 p3 = *(const float4*)&att[3][t0];
    const float pv0[4] = {p0.x, p0.y, p0.z, p0.w};
    const float pv1[4] = {p1.x, p1.y, p1.z, p1.w};
    const float pv2[4] = {p2.x, p2.y, p2.z, p2.w};
    const float pv3[4] = {p3.x, p3.y, p3.z, p3.w};
#pragma unroll
    for (int i = 0; i < 4; ++i) {
      const float ev = encb[(size_t)(t0 + i) << 9];
      acc0 = fmaf(pv0[i], ev, acc0);
      acc1 = fmaf(pv1[i], ev, acc1);
      acc2 = fmaf(pv2[i], ev, acc2);
      acc3 = fmaf(pv3[i], ev, acc3);
    }
  }
  if (h2 == 1) {
    ctx2[0][c] = acc0;
    ctx2[1][c] = acc1;
    ctx2[2][c] = acc2;
    ctx2[3][c] = acc3;
  }
  __syncthreads();
  if (h2 == 0) {
    acc0 += ctx2[0][c];
    acc1 += ctx2[1][c];
    acc2 += ctx2[2][c];
    acc3 += ctx2[3][c];
    float* __restrict__ cb = ctx + (((size_t)((b << 8) + s0)) << 9) + c;
    cb[0 * ED] = acc0;
    cb[1 * ED] = acc1;
    cb[2 * ED] = acc2;
    cb[3 * ED] = acc3;
  }
}

extern "C" void kernel_launch(void* const* d_in, const int* in_sizes, int n_in,
                              void* d_out, int out_size, void* d_ws, size_t ws_size,
                              hipStream_t stream) {
  const float* enc = (const float*)d_in[0];
  const float* dec = (const float*)d_in[1];
  const float* W1 = (const float*)d_in[2];
  const float* b1 = (const float*)d_in[3];
  const float* W2 = (const float*)d_in[4];
  const float* b2 = (const float*)d_in[5];
  const float* Vw = (const float*)d_in[6];
  // Vb cancels in softmax — unused.

  float* ctx = (float*)d_out;                          // (8,256,512)
  float* attn = (float*)d_out + (size_t)NB * TD * ED;  // (8,256,256)
  float* Epd = (float*)d_ws;                           // 512K floats
  float* EpeT2 = Epd + (size_t)NB * TD * DU;           // 512K floats

  proj_exp_kernel<<<dim3(512), dim3(512), 0, stream>>>(enc, dec, W1, b1, W2,
                                                       b2, Epd, EpeT2);
  score_ctx_kernel<<<dim3(512), dim3(1024), 0, stream>>>(Epd, EpeT2, Vw, enc,
                                                         attn, ctx);
}

// Round 8
// 55.638 us; speedup vs baseline: 1.7565x; 1.7565x over previous
//
#include <hip/hip_runtime.h>

#define NB 8
#define TE 256
#define TD 256
#define ED 512
#define DU 256

// EpeT2 layout: [b][uq=u/4][t][ui=u%4]  (64 x 256 x 4 floats per b = 65536)
// -> score reads one float4 (u-quad) per lane: 16B/lane, 1KB/wave.

// K1: proj+exp, 32x64 tiles, 512 threads (8 waves): K-split. Lower 256
// threads (h=0) accumulate K-half 0, upper (h=1) K-half 1; partials
// combined via LDS before epilogue. 2 blocks/CU x 8 waves = 4 waves/SIMD.
__global__ __launch_bounds__(512) void proj_exp_kernel(
    const float* __restrict__ enc, const float* __restrict__ dec,
    const float* __restrict__ W1, const float* __restrict__ b1,
    const float* __restrict__ W2, const float* __restrict__ b2,
    float* __restrict__ Epd, float* __restrict__ EpeT2)
{
  __shared__ __align__(16) float As[2][32][34];
  __shared__ __align__(16) float Bs[2][32][64];
  __shared__ __align__(16) float comb[8][256];
  const int blk = blockIdx.x;
  const bool is_pe = blk < 256;
  const int sub = blk & 255;
  const int K = is_pe ? ED : DU;
  const int NTh = K >> 6;  // K-tiles per half (pe: 8, pd: 4)
  const float* __restrict__ A = is_pe ? enc : dec;
  const float* __restrict__ W = is_pe ? W1 : W2;
  const float* __restrict__ bias = is_pe ? b1 : b2;
  const int mt = sub >> 2, nt = sub & 3;
  const int m0 = mt * 32, n0 = nt * 64;
  const int tid = threadIdx.x;
  const int t = tid & 255;  // index within half
  const int h = tid >> 8;   // K-half
  const int k0base = h * (K >> 1);
  const int tx = t & 15, ty = t >> 4;
  const int at = t >> 3, ka = (t & 7) << 2;   // A: row, k-offset
  const int kb = t >> 4, jb = (t & 15) << 2;  // W: k-row, col-offset

  const float* __restrict__ Ap = A + (size_t)(m0 + at) * K + k0base + ka;
  const float* __restrict__ Wp = W + (size_t)(k0base + kb) * DU + n0 + jb;

  float acc[2][4] = {};
  float4 aV, wV0, wV1;

  auto loadr = [&](int k0) {
    aV = *(const float4*)(Ap + k0);
    wV0 = *(const float4*)(Wp + (size_t)k0 * DU);
    wV1 = *(const float4*)(Wp + (size_t)(k0 + 16) * DU);
  };

  loadr(0);
  for (int kt = 0; kt < NTh; ++kt) {
    As[h][ka + 0][at] = aV.x;
    As[h][ka + 1][at] = aV.y;
    As[h][ka + 2][at] = aV.z;
    As[h][ka + 3][at] = aV.w;
    *(float4*)&Bs[h][kb][jb] = wV0;
    *(float4*)&Bs[h][kb + 16][jb] = wV1;
    __syncthreads();
    if (kt + 1 < NTh) loadr((kt + 1) << 5);
#pragma unroll
    for (int kk = 0; kk < 32; ++kk) {
      const float2 a2 = *(const float2*)&As[h][kk][ty * 2];
      const float4 w4 = *(const float4*)&Bs[h][kk][tx * 4];
      acc[0][0] = fmaf(a2.x, w4.x, acc[0][0]);
      acc[0][1] = fmaf(a2.x, w4.y, acc[0][1]);
      acc[0][2] = fmaf(a2.x, w4.z, acc[0][2]);
      acc[0][3] = fmaf(a2.x, w4.w, acc[0][3]);
      acc[1][0] = fmaf(a2.y, w4.x, acc[1][0]);
      acc[1][1] = fmaf(a2.y, w4.y, acc[1][1]);
      acc[1][2] = fmaf(a2.y, w4.z, acc[1][2]);
      acc[1][3] = fmaf(a2.y, w4.w, acc[1][3]);
    }
    __syncthreads();
  }

  // ---- combine K-halves ----
  if (h == 1) {
#pragma unroll
    for (int r = 0; r < 2; ++r)
#pragma unroll
      for (int j = 0; j < 4; ++j) comb[r * 4 + j][t] = acc[r][j];
  }
  __syncthreads();
  if (h == 0) {
#pragma unroll
    for (int r = 0; r < 2; ++r)
#pragma unroll
      for (int j = 0; j < 4; ++j) acc[r][j] += comb[r * 4 + j][t];

    const float4 bv4 = *(const float4*)(bias + n0 + tx * 4);
    const float bvv[4] = {bv4.x, bv4.y, bv4.z, bv4.w};
    if (is_pe) {
      // u-quad interleaved write: thread owns uq = n0/4+tx, t = t0+ty*2(+r)
      const int b = m0 >> 8, t0 = m0 & 255;
      const int uqg = (b << 6) + (n0 >> 2) + tx;
      const int tg = t0 + ty * 2;
      float* dst = EpeT2 + ((size_t)uqg << 10) + (tg << 2);
      float4 o0, o1;
      o0.x = __expf(2.0f * (acc[0][0] + bvv[0]));
      o0.y = __expf(2.0f * (acc[0][1] + bvv[1]));
      o0.z = __expf(2.0f * (acc[0][2] + bvv[2]));
      o0.w = __expf(2.0f * (acc[0][3] + bvv[3]));
      o1.x = __expf(2.0f * (acc[1][0] + bvv[0]));
      o1.y = __expf(2.0f * (acc[1][1] + bvv[1]));
      o1.z = __expf(2.0f * (acc[1][2] + bvv[2]));
      o1.w = __expf(2.0f * (acc[1][3] + bvv[3]));
      *(float4*)dst = o0;
      *(float4*)(dst + 4) = o1;
    } else {
#pragma unroll
      for (int r = 0; r < 2; ++r) {
        const int m = m0 + ty * 2 + r;  // global dec row (b*256+s)
        float4 o;
        o.x = __expf(2.0f * (acc[r][0] + bvv[0]));
        o.y = __expf(2.0f * (acc[r][1] + bvv[1]));
        o.z = __expf(2.0f * (acc[r][2] + bvv[2]));
        o.w = __expf(2.0f * (acc[r][3] + bvv[3]));
        *(float4*)(Epd + ((size_t)m << 8) + n0 + tx * 4) = o;
      }
    }
  }
}

// K23: fused score+softmax+context, 1024 threads (16 waves), grid 512 =
// (b, s-quad). R7 structure, but PLAIN __launch_bounds__(1024): the
// (1024,8) variant forced VGPR=32 -> ~20 regs spilled/thread -> 38MB
// scratch FETCH + 211MB WRITE per dispatch (R7, 90+us). Body needs ~52
// VGPR <= 64, so 2 blocks/CU (8 waves/SIMD) still fit WITHOUT the cap.
// Phase 1: u-QUARTER split (hq = tid>>8, 16 q-iters each) over LDS-staged
// Epd rows + Vw (broadcast ds_read) and per-lane EpeT2 float4 loads
// (prefetched one iter ahead). Partials combined via 12KB LDS.
// Softmax: no-max variant (|score| <= 2*sum|Vw| ~ 26, fp32-safe; validated
// R6/R7) on the low 4 waves.
// Phase 2: t-half split (h2 = tid>>9); thread owns ctx col c=tid&511 x 4
// rows over its t-half; partials combined via 8KB LDS. enc read once/block.
__global__ __launch_bounds__(1024) void score_ctx_kernel(
    const float* __restrict__ Epd, const float* __restrict__ EpeT2,
    const float* __restrict__ Vw, const float* __restrict__ enc,
    float* __restrict__ attn, float* __restrict__ ctx)
{
  __shared__ __align__(16) float eps[4 * 256];     // Epd rows (4KB)
  __shared__ __align__(16) float vws[256];         // Vw (1KB)
  __shared__ __align__(16) float comb[3][4][256];  // u-quarter partials (12KB)
  __shared__ __align__(16) float att[4][256];      // probs (4KB)
  __shared__ __align__(16) float ctx2[4][512];     // t-half partials (8KB)
  __shared__ float reds[4][4];

  const int blk0 = blockIdx.x;
  const int blk = ((blk0 & 7) << 6) | (blk0 >> 3);  // T1 XCD swizzle
  const int b = blk >> 6;
  const int s0 = (blk & 63) << 2;
  const int tid = threadIdx.x;
  const int t = tid & 255;   // enc position
  const int hq = tid >> 8;   // u-quarter (0..3)

  // ---- stage Epd 4 rows (contiguous 4KB) + Vw (1KB) into LDS ----
  if (hq == 0) {
    ((float4*)eps)[t] =
        ((const float4*)(Epd + (((size_t)((b << 8) + s0)) << 8)))[t];
  } else if (hq == 1 && t < 64) {
    ((float4*)vws)[t] = ((const float4*)Vw)[t];
  }
  __syncthreads();

  // ---- Phase 1: score partials for u-quarter hq (q = hq*16 .. +15) ----
  const int qb = hq << 4;
  const float* __restrict__ ep =
      EpeT2 + ((size_t)b << 16) + ((size_t)qb << 10) + (t << 2);

  float a0 = 0.f, a1 = 0.f, a2 = 0.f, a3 = 0.f;
  float4 g = *(const float4*)ep;
#pragma unroll 4
  for (int q = 0; q < 16; ++q) {
    float4 gn;
    if (q + 1 < 16) gn = *(const float4*)(ep + ((size_t)(q + 1) << 10));
    const int u4 = (qb + q) << 2;
    const float4 vw = *(const float4*)&vws[u4];
    const float4 e0 = *(const float4*)&eps[u4];
    const float4 e1 = *(const float4*)&eps[256 + u4];
    const float4 e2 = *(const float4*)&eps[512 + u4];
    const float4 e3 = *(const float4*)&eps[768 + u4];
    a0 = fmaf(vw.x, __builtin_amdgcn_rcpf(fmaf(e0.x, g.x, 1.0f)), a0);
    a1 = fmaf(vw.x, __builtin_amdgcn_rcpf(fmaf(e1.x, g.x, 1.0f)), a1);
    a2 = fmaf(vw.x, __builtin_amdgcn_rcpf(fmaf(e2.x, g.x, 1.0f)), a2);
    a3 = fmaf(vw.x, __builtin_amdgcn_rcpf(fmaf(e3.x, g.x, 1.0f)), a3);
    a0 = fmaf(vw.y, __builtin_amdgcn_rcpf(fmaf(e0.y, g.y, 1.0f)), a0);
    a1 = fmaf(vw.y, __builtin_amdgcn_rcpf(fmaf(e1.y, g.y, 1.0f)), a1);
    a2 = fmaf(vw.y, __builtin_amdgcn_rcpf(fmaf(e2.y, g.y, 1.0f)), a2);
    a3 = fmaf(vw.y, __builtin_amdgcn_rcpf(fmaf(e3.y, g.y, 1.0f)), a3);
    a0 = fmaf(vw.z, __builtin_amdgcn_rcpf(fmaf(e0.z, g.z, 1.0f)), a0);
    a1 = fmaf(vw.z, __builtin_amdgcn_rcpf(fmaf(e1.z, g.z, 1.0f)), a1);
    a2 = fmaf(vw.z, __builtin_amdgcn_rcpf(fmaf(e2.z, g.z, 1.0f)), a2);
    a3 = fmaf(vw.z, __builtin_amdgcn_rcpf(fmaf(e3.z, g.z, 1.0f)), a3);
    a0 = fmaf(vw.w, __builtin_amdgcn_rcpf(fmaf(e0.w, g.w, 1.0f)), a0);
    a1 = fmaf(vw.w, __builtin_amdgcn_rcpf(fmaf(e1.w, g.w, 1.0f)), a1);
    a2 = fmaf(vw.w, __builtin_amdgcn_rcpf(fmaf(e2.w, g.w, 1.0f)), a2);
    a3 = fmaf(vw.w, __builtin_amdgcn_rcpf(fmaf(e3.w, g.w, 1.0f)), a3);
    g = gn;
  }

  if (hq != 0) {
    comb[hq - 1][0][t] = a0;
    comb[hq - 1][1][t] = a1;
    comb[hq - 1][2][t] = a2;
    comb[hq - 1][3][t] = a3;
  }
  __syncthreads();

  // ---- combine + no-max softmax on lowest 4 waves ----
  const int wid = tid >> 6, lane = tid & 63;
  float e[4];
  if (hq == 0) {
    float vv[4];
    vv[0] = a0 + comb[0][0][t] + comb[1][0][t] + comb[2][0][t];
    vv[1] = a1 + comb[0][1][t] + comb[1][1][t] + comb[2][1][t];
    vv[2] = a2 + comb[0][2][t] + comb[1][2][t] + comb[2][2][t];
    vv[3] = a3 + comb[0][3][t] + comb[1][3][t] + comb[2][3][t];
#pragma unroll
    for (int r = 0; r < 4; ++r) {
      e[r] = __expf(-2.f * vv[r]);
      float s = e[r];
#pragma unroll
      for (int off = 32; off; off >>= 1) s += __shfl_xor(s, off);
      if (lane == 0) reds[r][wid] = s;
    }
  }
  __syncthreads();
  if (hq == 0) {
#pragma unroll
    for (int r = 0; r < 4; ++r) {
      const float s = (reds[r][0] + reds[r][1]) + (reds[r][2] + reds[r][3]);
      const float p = e[r] * __builtin_amdgcn_rcpf(s);
      attn[(((size_t)((b << 8) + s0 + r)) << 8) + t] = p;
      att[r][t] = p;
    }
  }
  __syncthreads();

  // ---- Phase 2: ctx col c, 4 rows, t-half h2. enc read once per block. ----
  const int c = tid & 511;
  const int h2 = tid >> 9;
  const int tb = h2 << 7;
  const float* __restrict__ encb = enc + ((size_t)b << 17) + c;
  float acc0 = 0.f, acc1 = 0.f, acc2 = 0.f, acc3 = 0.f;
#pragma unroll 2
  for (int t0 = tb; t0 < tb + 128; t0 += 4) {
    const float4 p0 = *(const float4*)&att[0][t0];
    const float4 p1 = *(const float4*)&att[1][t0];
    const float4 p2 = *(const float4*)&att[2][t0];
    const float4 p3 = *(const float4*)&att[3][t0];
    const float pv0[4] = {p0.x, p0.y, p0.z, p0.w};
    const float pv1[4] = {p1.x, p1.y, p1.z, p1.w};
    const float pv2[4] = {p2.x, p2.y, p2.z, p2.w};
    const float pv3[4] = {p3.x, p3.y, p3.z, p3.w};
#pragma unroll
    for (int i = 0; i < 4; ++i) {
      const float ev = encb[(size_t)(t0 + i) << 9];
      acc0 = fmaf(pv0[i], ev, acc0);
      acc1 = fmaf(pv1[i], ev, acc1);
      acc2 = fmaf(pv2[i], ev, acc2);
      acc3 = fmaf(pv3[i], ev, acc3);
    }
  }
  if (h2 == 1) {
    ctx2[0][c] = acc0;
    ctx2[1][c] = acc1;
    ctx2[2][c] = acc2;
    ctx2[3][c] = acc3;
  }
  __syncthreads();
  if (h2 == 0) {
    acc0 += ctx2[0][c];
    acc1 += ctx2[1][c];
    acc2 += ctx2[2][c];
    acc3 += ctx2[3][c];
    float* __restrict__ cb = ctx + (((size_t)((b << 8) + s0)) << 9) + c;
    cb[0 * ED] = acc0;
    cb[1 * ED] = acc1;
    cb[2 * ED] = acc2;
    cb[3 * ED] = acc3;
  }
}

extern "C" void kernel_launch(void* const* d_in, const int* in_sizes, int n_in,
                              void* d_out, int out_size, void* d_ws, size_t ws_size,
                              hipStream_t stream) {
  const float* enc = (const float*)d_in[0];
  const float* dec = (const float*)d_in[1];
  const float* W1 = (const float*)d_in[2];
  const float* b1 = (const float*)d_in[3];
  const float* W2 = (const float*)d_in[4];
  const float* b2 = (const float*)d_in[5];
  const float* Vw = (const float*)d_in[6];
  // Vb cancels in softmax — unused.

  float* ctx = (float*)d_out;                          // (8,256,512)
  float* attn = (float*)d_out + (size_t)NB * TD * ED;  // (8,256,256)
  float* Epd = (float*)d_ws;                           // 512K floats
  float* EpeT2 = Epd + (size_t)NB * TD * DU;           // 512K floats

  proj_exp_kernel<<<dim3(512), dim3(512), 0, stream>>>(enc, dec, W1, b1, W2,
                                                       b2, Epd, EpeT2);
  score_ctx_kernel<<<dim3(512), dim3(1024), 0, stream>>>(Epd, EpeT2, Vw, enc,
                                                         attn, ctx);
}

// Round 9
// 48.320 us; speedup vs baseline: 2.0225x; 1.1515x over previous
//
#include <hip/hip_runtime.h>

#define NB 8
#define TE 256
#define TD 256
#define ED 512
#define DU 256

// EpeT2 layout: [b][uq=u/4][t][ui=u%4]  (64 x 256 x 4 floats per b = 65536)

// K1: proj+exp, 32x64 tiles, 512 threads (8 waves): K-split (R5 form,
// best measured). 2 blocks/CU x 8 waves = 4 waves/SIMD.
__global__ __launch_bounds__(512) void proj_exp_kernel(
    const float* __restrict__ enc, const float* __restrict__ dec,
    const float* __restrict__ W1, const float* __restrict__ b1,
    const float* __restrict__ W2, const float* __restrict__ b2,
    float* __restrict__ Epd, float* __restrict__ EpeT2)
{
  __shared__ __align__(16) float As[2][32][34];
  __shared__ __align__(16) float Bs[2][32][64];
  __shared__ __align__(16) float comb[8][256];
  const int blk = blockIdx.x;
  const bool is_pe = blk < 256;
  const int sub = blk & 255;
  const int K = is_pe ? ED : DU;
  const int NTh = K >> 6;  // K-tiles per half (pe: 8, pd: 4)
  const float* __restrict__ A = is_pe ? enc : dec;
  const float* __restrict__ W = is_pe ? W1 : W2;
  const float* __restrict__ bias = is_pe ? b1 : b2;
  const int mt = sub >> 2, nt = sub & 3;
  const int m0 = mt * 32, n0 = nt * 64;
  const int tid = threadIdx.x;
  const int t = tid & 255;  // index within half
  const int h = tid >> 8;   // K-half
  const int k0base = h * (K >> 1);
  const int tx = t & 15, ty = t >> 4;
  const int at = t >> 3, ka = (t & 7) << 2;   // A: row, k-offset
  const int kb = t >> 4, jb = (t & 15) << 2;  // W: k-row, col-offset

  const float* __restrict__ Ap = A + (size_t)(m0 + at) * K + k0base + ka;
  const float* __restrict__ Wp = W + (size_t)(k0base + kb) * DU + n0 + jb;

  float acc[2][4] = {};
  float4 aV, wV0, wV1;

  auto loadr = [&](int k0) {
    aV = *(const float4*)(Ap + k0);
    wV0 = *(const float4*)(Wp + (size_t)k0 * DU);
    wV1 = *(const float4*)(Wp + (size_t)(k0 + 16) * DU);
  };

  loadr(0);
  for (int kt = 0; kt < NTh; ++kt) {
    As[h][ka + 0][at] = aV.x;
    As[h][ka + 1][at] = aV.y;
    As[h][ka + 2][at] = aV.z;
    As[h][ka + 3][at] = aV.w;
    *(float4*)&Bs[h][kb][jb] = wV0;
    *(float4*)&Bs[h][kb + 16][jb] = wV1;
    __syncthreads();
    if (kt + 1 < NTh) loadr((kt + 1) << 5);
#pragma unroll
    for (int kk = 0; kk < 32; ++kk) {
      const float2 a2 = *(const float2*)&As[h][kk][ty * 2];
      const float4 w4 = *(const float4*)&Bs[h][kk][tx * 4];
      acc[0][0] = fmaf(a2.x, w4.x, acc[0][0]);
      acc[0][1] = fmaf(a2.x, w4.y, acc[0][1]);
      acc[0][2] = fmaf(a2.x, w4.z, acc[0][2]);
      acc[0][3] = fmaf(a2.x, w4.w, acc[0][3]);
      acc[1][0] = fmaf(a2.y, w4.x, acc[1][0]);
      acc[1][1] = fmaf(a2.y, w4.y, acc[1][1]);
      acc[1][2] = fmaf(a2.y, w4.z, acc[1][2]);
      acc[1][3] = fmaf(a2.y, w4.w, acc[1][3]);
    }
    __syncthreads();
  }

  // ---- combine K-halves ----
  if (h == 1) {
#pragma unroll
    for (int r = 0; r < 2; ++r)
#pragma unroll
      for (int j = 0; j < 4; ++j) comb[r * 4 + j][t] = acc[r][j];
  }
  __syncthreads();
  if (h == 0) {
#pragma unroll
    for (int r = 0; r < 2; ++r)
#pragma unroll
      for (int j = 0; j < 4; ++j) acc[r][j] += comb[r * 4 + j][t];

    const float4 bv4 = *(const float4*)(bias + n0 + tx * 4);
    const float bvv[4] = {bv4.x, bv4.y, bv4.z, bv4.w};
    if (is_pe) {
      const int b = m0 >> 8, t0 = m0 & 255;
      const int uqg = (b << 6) + (n0 >> 2) + tx;
      const int tg = t0 + ty * 2;
      float* dst = EpeT2 + ((size_t)uqg << 10) + (tg << 2);
      float4 o0, o1;
      o0.x = __expf(2.0f * (acc[0][0] + bvv[0]));
      o0.y = __expf(2.0f * (acc[0][1] + bvv[1]));
      o0.z = __expf(2.0f * (acc[0][2] + bvv[2]));
      o0.w = __expf(2.0f * (acc[0][3] + bvv[3]));
      o1.x = __expf(2.0f * (acc[1][0] + bvv[0]));
      o1.y = __expf(2.0f * (acc[1][1] + bvv[1]));
      o1.z = __expf(2.0f * (acc[1][2] + bvv[2]));
      o1.w = __expf(2.0f * (acc[1][3] + bvv[3]));
      *(float4*)dst = o0;
      *(float4*)(dst + 4) = o1;
    } else {
#pragma unroll
      for (int r = 0; r < 2; ++r) {
        const int m = m0 + ty * 2 + r;
        float4 o;
        o.x = __expf(2.0f * (acc[r][0] + bvv[0]));
        o.y = __expf(2.0f * (acc[r][1] + bvv[1]));
        o.z = __expf(2.0f * (acc[r][2] + bvv[2]));
        o.w = __expf(2.0f * (acc[r][3] + bvv[3]));
        *(float4*)(Epd + ((size_t)m << 8) + n0 + tx * 4) = o;
      }
    }
  }
}

// K23: fused score+softmax+context, 512 threads (8 waves), grid 512 =
// (b, s-quad), XCD swizzle. Phase 1 = R5 form (u-half split, LDS-staged
// Epd/Vw, g prefetch). Softmax: no-max (validated R6-R8).
// Phase 2 REDESIGNED for LDS-pipe relief (R8 falsified the TLP theory;
// model says broadcast ds_read count was the binding resource):
// thread owns 4 CONSECUTIVE cols c4=4*(tid&127) x 4 rows x t-quarter
// tq=tid>>7. Each p ds_read_b128 (4 floats) now feeds 16 FMA (was 4)
// -> phase-2 LDS reads/wave drop 256 -> 64+12. enc read as float4,
// 1KB/wave fully coalesced, each element once per block. t-quarter
// partials combined via 24KB LDS tree at the end.
__global__ __launch_bounds__(512) void score_ctx_kernel(
    const float* __restrict__ Epd, const float* __restrict__ EpeT2,
    const float* __restrict__ Vw, const float* __restrict__ enc,
    float* __restrict__ attn, float* __restrict__ ctx)
{
  __shared__ __align__(16) float eps[4 * 256];     // Epd rows (4KB)
  __shared__ __align__(16) float vws[256];         // Vw (1KB)
  __shared__ __align__(16) float comb[4][256];     // u-half partials (4KB)
  __shared__ __align__(16) float att[4][256];      // probs (4KB)
  __shared__ __align__(16) float ctx2[3][4][512];  // t-quarter partials (24KB)
  __shared__ float reds[4][4];

  const int blk0 = blockIdx.x;
  const int blk = ((blk0 & 7) << 6) | (blk0 >> 3);  // T1 XCD swizzle
  const int b = blk >> 6;
  const int s0 = (blk & 63) << 2;
  const int tid = threadIdx.x;
  const int t = tid & 255;  // enc position
  const int h = tid >> 8;   // u-half (0/1)

  // ---- stage Epd 4 rows (contiguous 4KB) + Vw (1KB) into LDS ----
  if (h == 0) {
    ((float4*)eps)[t] =
        ((const float4*)(Epd + (((size_t)((b << 8) + s0)) << 8)))[t];
  } else if (t < 64) {
    ((float4*)vws)[t] = ((const float4*)Vw)[t];
  }
  __syncthreads();

  // ---- Phase 1: score partials for u-half h (q = h*32 .. h*32+31) ----
  const float* __restrict__ ep =
      EpeT2 + ((size_t)b << 16) + ((size_t)h << 15) + (t << 2);
  const int qb = h << 5;

  float a0 = 0.f, a1 = 0.f, a2 = 0.f, a3 = 0.f;
  float4 g = *(const float4*)ep;
#pragma unroll 4
  for (int q = 0; q < 32; ++q) {
    float4 gn;
    if (q + 1 < 32) gn = *(const float4*)(ep + ((size_t)(q + 1) << 10));
    const int u4 = (qb + q) << 2;
    const float4 vw = *(const float4*)&vws[u4];
    const float4 e0 = *(const float4*)&eps[u4];
    const float4 e1 = *(const float4*)&eps[256 + u4];
    const float4 e2 = *(const float4*)&eps[512 + u4];
    const float4 e3 = *(const float4*)&eps[768 + u4];
    a0 = fmaf(vw.x, __builtin_amdgcn_rcpf(fmaf(e0.x, g.x, 1.0f)), a0);
    a1 = fmaf(vw.x, __builtin_amdgcn_rcpf(fmaf(e1.x, g.x, 1.0f)), a1);
    a2 = fmaf(vw.x, __builtin_amdgcn_rcpf(fmaf(e2.x, g.x, 1.0f)), a2);
    a3 = fmaf(vw.x, __builtin_amdgcn_rcpf(fmaf(e3.x, g.x, 1.0f)), a3);
    a0 = fmaf(vw.y, __builtin_amdgcn_rcpf(fmaf(e0.y, g.y, 1.0f)), a0);
    a1 = fmaf(vw.y, __builtin_amdgcn_rcpf(fmaf(e1.y, g.y, 1.0f)), a1);
    a2 = fmaf(vw.y, __builtin_amdgcn_rcpf(fmaf(e2.y, g.y, 1.0f)), a2);
    a3 = fmaf(vw.y, __builtin_amdgcn_rcpf(fmaf(e3.y, g.y, 1.0f)), a3);
    a0 = fmaf(vw.z, __builtin_amdgcn_rcpf(fmaf(e0.z, g.z, 1.0f)), a0);
    a1 = fmaf(vw.z, __builtin_amdgcn_rcpf(fmaf(e1.z, g.z, 1.0f)), a1);
    a2 = fmaf(vw.z, __builtin_amdgcn_rcpf(fmaf(e2.z, g.z, 1.0f)), a2);
    a3 = fmaf(vw.z, __builtin_amdgcn_rcpf(fmaf(e3.z, g.z, 1.0f)), a3);
    a0 = fmaf(vw.w, __builtin_amdgcn_rcpf(fmaf(e0.w, g.w, 1.0f)), a0);
    a1 = fmaf(vw.w, __builtin_amdgcn_rcpf(fmaf(e1.w, g.w, 1.0f)), a1);
    a2 = fmaf(vw.w, __builtin_amdgcn_rcpf(fmaf(e2.w, g.w, 1.0f)), a2);
    a3 = fmaf(vw.w, __builtin_amdgcn_rcpf(fmaf(e3.w, g.w, 1.0f)), a3);
    g = gn;
  }

  if (h == 1) {
    comb[0][t] = a0;
    comb[1][t] = a1;
    comb[2][t] = a2;
    comb[3][t] = a3;
  }
  __syncthreads();

  // ---- combine + no-max softmax on lower 4 waves ----
  const int wid = tid >> 6, lane = tid & 63;
  float e[4];
  if (h == 0) {
    float vv[4];
    vv[0] = a0 + comb[0][t];
    vv[1] = a1 + comb[1][t];
    vv[2] = a2 + comb[2][t];
    vv[3] = a3 + comb[3][t];
#pragma unroll
    for (int r = 0; r < 4; ++r) {
      e[r] = __expf(-2.f * vv[r]);
      float s = e[r];
#pragma unroll
      for (int off = 32; off; off >>= 1) s += __shfl_xor(s, off);
      if (lane == 0) reds[r][wid] = s;
    }
  }
  __syncthreads();
  if (h == 0) {
#pragma unroll
    for (int r = 0; r < 4; ++r) {
      const float s = (reds[r][0] + reds[r][1]) + (reds[r][2] + reds[r][3]);
      const float p = e[r] * __builtin_amdgcn_rcpf(s);
      attn[(((size_t)((b << 8) + s0 + r)) << 8) + t] = p;
      att[r][t] = p;
    }
  }
  __syncthreads();

  // ---- Phase 2: thread owns cols c4..c4+3, rows s0..s0+3, t-quarter tq.
  const int c4 = (tid & 127) << 2;
  const int tq = tid >> 7;  // 0..3
  const int tb = tq << 6;   // 64 t per quarter
  const float* __restrict__ encb = enc + ((size_t)b << 17) + c4;
  float4 acc0 = {0.f, 0.f, 0.f, 0.f};
  float4 acc1 = {0.f, 0.f, 0.f, 0.f};
  float4 acc2 = {0.f, 0.f, 0.f, 0.f};
  float4 acc3 = {0.f, 0.f, 0.f, 0.f};
#pragma unroll 2
  for (int t0 = tb; t0 < tb + 64; t0 += 4) {
    const float4 p0 = *(const float4*)&att[0][t0];
    const float4 p1 = *(const float4*)&att[1][t0];
    const float4 p2 = *(const float4*)&att[2][t0];
    const float4 p3 = *(const float4*)&att[3][t0];
    const float pv0[4] = {p0.x, p0.y, p0.z, p0.w};
    const float pv1[4] = {p1.x, p1.y, p1.z, p1.w};
    const float pv2[4] = {p2.x, p2.y, p2.z, p2.w};
    const float pv3[4] = {p3.x, p3.y, p3.z, p3.w};
#pragma unroll
    for (int i = 0; i < 4; ++i) {
      const float4 ev = *(const float4*)(encb + ((size_t)(t0 + i) << 9));
      acc0.x = fmaf(pv0[i], ev.x, acc0.x);
      acc0.y = fmaf(pv0[i], ev.y, acc0.y);
      acc0.z = fmaf(pv0[i], ev.z, acc0.z);
      acc0.w = fmaf(pv0[i], ev.w, acc0.w);
      acc1.x = fmaf(pv1[i], ev.x, acc1.x);
      acc1.y = fmaf(pv1[i], ev.y, acc1.y);
      acc1.z = fmaf(pv1[i], ev.z, acc1.z);
      acc1.w = fmaf(pv1[i], ev.w, acc1.w);
      acc2.x = fmaf(pv2[i], ev.x, acc2.x);
      acc2.y = fmaf(pv2[i], ev.y, acc2.y);
      acc2.z = fmaf(pv2[i], ev.z, acc2.z);
      acc2.w = fmaf(pv2[i], ev.w, acc2.w);
      acc3.x = fmaf(pv3[i], ev.x, acc3.x);
      acc3.y = fmaf(pv3[i], ev.y, acc3.y);
      acc3.z = fmaf(pv3[i], ev.z, acc3.z);
      acc3.w = fmaf(pv3[i], ev.w, acc3.w);
    }
  }
  if (tq != 0) {
    *(float4*)&ctx2[tq - 1][0][c4] = acc0;
    *(float4*)&ctx2[tq - 1][1][c4] = acc1;
    *(float4*)&ctx2[tq - 1][2][c4] = acc2;
    *(float4*)&ctx2[tq - 1][3][c4] = acc3;
  }
  __syncthreads();
  if (tq == 0) {
#pragma unroll
    for (int q = 0; q < 3; ++q) {
      const float4 q0 = *(const float4*)&ctx2[q][0][c4];
      const float4 q1 = *(const float4*)&ctx2[q][1][c4];
      const float4 q2 = *(const float4*)&ctx2[q][2][c4];
      const float4 q3 = *(const float4*)&ctx2[q][3][c4];
      acc0.x += q0.x; acc0.y += q0.y; acc0.z += q0.z; acc0.w += q0.w;
      acc1.x += q1.x; acc1.y += q1.y; acc1.z += q1.z; acc1.w += q1.w;
      acc2.x += q2.x; acc2.y += q2.y; acc2.z += q2.z; acc2.w += q2.w;
      acc3.x += q3.x; acc3.y += q3.y; acc3.z += q3.z; acc3.w += q3.w;
    }
    float* __restrict__ cb = ctx + (((size_t)((b << 8) + s0)) << 9) + c4;
    *(float4*)(cb + 0 * ED) = acc0;
    *(float4*)(cb + 1 * ED) = acc1;
    *(float4*)(cb + 2 * ED) = acc2;
    *(float4*)(cb + 3 * ED) = acc3;
  }
}

extern "C" void kernel_launch(void* const* d_in, const int* in_sizes, int n_in,
                              void* d_out, int out_size, void* d_ws, size_t ws_size,
                              hipStream_t stream) {
  const float* enc = (const float*)d_in[0];
  const float* dec = (const float*)d_in[1];
  const float* W1 = (const float*)d_in[2];
  const float* b1 = (const float*)d_in[3];
  const float* W2 = (const float*)d_in[4];
  const float* b2 = (const float*)d_in[5];
  const float* Vw = (const float*)d_in[6];
  // Vb cancels in softmax — unused.

  float* ctx = (float*)d_out;                          // (8,256,512)
  float* attn = (float*)d_out + (size_t)NB * TD * ED;  // (8,256,256)
  float* Epd = (float*)d_ws;                           // 512K floats
  float* EpeT2 = Epd + (size_t)NB * TD * DU;           // 512K floats

  proj_exp_kernel<<<dim3(512), dim3(512), 0, stream>>>(enc, dec, W1, b1, W2,
                                                       b2, Epd, EpeT2);
  score_ctx_kernel<<<dim3(512), dim3(512), 0, stream>>>(Epd, EpeT2, Vw, enc,
                                                        attn, ctx);
}

// Round 10
// 47.530 us; speedup vs baseline: 2.0561x; 1.0166x over previous
//
#include <hip/hip_runtime.h>

#define NB 8
#define TE 256
#define TD 256
#define ED 512
#define DU 256

// EpeT2 layout: [b][uq=u/4][t][ui=u%4]  (64 x 256 x 4 floats per b = 65536)

// K1: proj+exp, 32x64 tiles, 512 threads (8 waves): K-split (R5 form,
// best measured). 2 blocks/CU x 8 waves = 4 waves/SIMD.
__global__ __launch_bounds__(512) void proj_exp_kernel(
    const float* __restrict__ enc, const float* __restrict__ dec,
    const float* __restrict__ W1, const float* __restrict__ b1,
    const float* __restrict__ W2, const float* __restrict__ b2,
    float* __restrict__ Epd, float* __restrict__ EpeT2)
{
  __shared__ __align__(16) float As[2][32][34];
  __shared__ __align__(16) float Bs[2][32][64];
  __shared__ __align__(16) float comb[8][256];
  const int blk = blockIdx.x;
  const bool is_pe = blk < 256;
  const int sub = blk & 255;
  const int K = is_pe ? ED : DU;
  const int NTh = K >> 6;  // K-tiles per half (pe: 8, pd: 4)
  const float* __restrict__ A = is_pe ? enc : dec;
  const float* __restrict__ W = is_pe ? W1 : W2;
  const float* __restrict__ bias = is_pe ? b1 : b2;
  const int mt = sub >> 2, nt = sub & 3;
  const int m0 = mt * 32, n0 = nt * 64;
  const int tid = threadIdx.x;
  const int t = tid & 255;  // index within half
  const int h = tid >> 8;   // K-half
  const int k0base = h * (K >> 1);
  const int tx = t & 15, ty = t >> 4;
  const int at = t >> 3, ka = (t & 7) << 2;   // A: row, k-offset
  const int kb = t >> 4, jb = (t & 15) << 2;  // W: k-row, col-offset

  const float* __restrict__ Ap = A + (size_t)(m0 + at) * K + k0base + ka;
  const float* __restrict__ Wp = W + (size_t)(k0base + kb) * DU + n0 + jb;

  float acc[2][4] = {};
  float4 aV, wV0, wV1;

  auto loadr = [&](int k0) {
    aV = *(const float4*)(Ap + k0);
    wV0 = *(const float4*)(Wp + (size_t)k0 * DU);
    wV1 = *(const float4*)(Wp + (size_t)(k0 + 16) * DU);
  };

  loadr(0);
  for (int kt = 0; kt < NTh; ++kt) {
    As[h][ka + 0][at] = aV.x;
    As[h][ka + 1][at] = aV.y;
    As[h][ka + 2][at] = aV.z;
    As[h][ka + 3][at] = aV.w;
    *(float4*)&Bs[h][kb][jb] = wV0;
    *(float4*)&Bs[h][kb + 16][jb] = wV1;
    __syncthreads();
    if (kt + 1 < NTh) loadr((kt + 1) << 5);
#pragma unroll
    for (int kk = 0; kk < 32; ++kk) {
      const float2 a2 = *(const float2*)&As[h][kk][ty * 2];
      const float4 w4 = *(const float4*)&Bs[h][kk][tx * 4];
      acc[0][0] = fmaf(a2.x, w4.x, acc[0][0]);
      acc[0][1] = fmaf(a2.x, w4.y, acc[0][1]);
      acc[0][2] = fmaf(a2.x, w4.z, acc[0][2]);
      acc[0][3] = fmaf(a2.x, w4.w, acc[0][3]);
      acc[1][0] = fmaf(a2.y, w4.x, acc[1][0]);
      acc[1][1] = fmaf(a2.y, w4.y, acc[1][1]);
      acc[1][2] = fmaf(a2.y, w4.z, acc[1][2]);
      acc[1][3] = fmaf(a2.y, w4.w, acc[1][3]);
    }
    __syncthreads();
  }

  // ---- combine K-halves ----
  if (h == 1) {
#pragma unroll
    for (int r = 0; r < 2; ++r)
#pragma unroll
      for (int j = 0; j < 4; ++j) comb[r * 4 + j][t] = acc[r][j];
  }
  __syncthreads();
  if (h == 0) {
#pragma unroll
    for (int r = 0; r < 2; ++r)
#pragma unroll
      for (int j = 0; j < 4; ++j) acc[r][j] += comb[r * 4 + j][t];

    const float4 bv4 = *(const float4*)(bias + n0 + tx * 4);
    const float bvv[4] = {bv4.x, bv4.y, bv4.z, bv4.w};
    if (is_pe) {
      const int b = m0 >> 8, t0 = m0 & 255;
      const int uqg = (b << 6) + (n0 >> 2) + tx;
      const int tg = t0 + ty * 2;
      float* dst = EpeT2 + ((size_t)uqg << 10) + (tg << 2);
      float4 o0, o1;
      o0.x = __expf(2.0f * (acc[0][0] + bvv[0]));
      o0.y = __expf(2.0f * (acc[0][1] + bvv[1]));
      o0.z = __expf(2.0f * (acc[0][2] + bvv[2]));
      o0.w = __expf(2.0f * (acc[0][3] + bvv[3]));
      o1.x = __expf(2.0f * (acc[1][0] + bvv[0]));
      o1.y = __expf(2.0f * (acc[1][1] + bvv[1]));
      o1.z = __expf(2.0f * (acc[1][2] + bvv[2]));
      o1.w = __expf(2.0f * (acc[1][3] + bvv[3]));
      *(float4*)dst = o0;
      *(float4*)(dst + 4) = o1;
    } else {
#pragma unroll
      for (int r = 0; r < 2; ++r) {
        const int m = m0 + ty * 2 + r;
        float4 o;
        o.x = __expf(2.0f * (acc[r][0] + bvv[0]));
        o.y = __expf(2.0f * (acc[r][1] + bvv[1]));
        o.z = __expf(2.0f * (acc[r][2] + bvv[2]));
        o.w = __expf(2.0f * (acc[r][3] + bvv[3]));
        *(float4*)(Epd + ((size_t)m << 8) + n0 + tx * 4) = o;
      }
    }
  }
}

// K23: fused score+softmax+context, 512 threads (8 waves), grid 512 =
// (b, s-quad), XCD swizzle.
// Phase 1 re-mapped for LDS-read reuse (R9 confirmed the LDS-pipe model):
// thread = (t-pair p = tid&127 -> t in {p, p+128}, u-quarter hq = tid>>7),
// 16 q-iters. The 5 broadcast ds_read_b128 (vw, e0..e3) per iter now feed
// 2 t-columns: 64 FMA + 32 rcp per read-group (2x R9's reuse) -> phase-1
// ds_read count halves. Partials (4 quarters x 4 rows x 256 t) combined
// via 16KB LDS; softmax (no-max, validated R6-R9) on threads 0..255 in the
// plain t-mapping.
// Phase 2 unchanged from R9: 4 cols/thread x t-quarter, 24KB combine.
__global__ __launch_bounds__(512) void score_ctx_kernel(
    const float* __restrict__ Epd, const float* __restrict__ EpeT2,
    const float* __restrict__ Vw, const float* __restrict__ enc,
    float* __restrict__ attn, float* __restrict__ ctx)
{
  __shared__ __align__(16) float eps[4 * 256];     // Epd rows (4KB)
  __shared__ __align__(16) float vws[256];         // Vw (1KB)
  __shared__ __align__(16) float comb[4][4][256];  // u-quarter partials (16KB)
  __shared__ __align__(16) float att[4][256];      // probs (4KB)
  __shared__ __align__(16) float ctx2[3][4][512];  // t-quarter partials (24KB)
  __shared__ float reds[4][4];

  const int blk0 = blockIdx.x;
  const int blk = ((blk0 & 7) << 6) | (blk0 >> 3);  // T1 XCD swizzle
  const int b = blk >> 6;
  const int s0 = (blk & 63) << 2;
  const int tid = threadIdx.x;

  // ---- stage Epd 4 rows (contiguous 4KB) + Vw (1KB) into LDS ----
  if (tid < 256) {
    ((float4*)eps)[tid] =
        ((const float4*)(Epd + (((size_t)((b << 8) + s0)) << 8)))[tid];
  } else if (tid < 320) {
    ((float4*)vws)[tid - 256] = ((const float4*)Vw)[tid - 256];
  }
  __syncthreads();

  // ---- Phase 1: u-quarter hq, t-pair {p, p+128} ----
  const int p = tid & 127;
  const int hq = tid >> 7;  // 0..3 (wave-uniform: 2 waves per quarter)
  const int qb = hq << 4;   // 16 q per quarter
  const float* __restrict__ epA =
      EpeT2 + ((size_t)b << 16) + ((size_t)qb << 10) + (p << 2);
  const float* __restrict__ epB = epA + (128 << 2);

  float accA[4] = {};  // rows, t = p
  float accB[4] = {};  // rows, t = p+128
  float4 ga = *(const float4*)epA;
  float4 gb = *(const float4*)epB;
#pragma unroll 4
  for (int q = 0; q < 16; ++q) {
    float4 gan, gbn;
    if (q + 1 < 16) {
      gan = *(const float4*)(epA + ((size_t)(q + 1) << 10));
      gbn = *(const float4*)(epB + ((size_t)(q + 1) << 10));
    }
    const int u4 = (qb + q) << 2;
    const float4 vw = *(const float4*)&vws[u4];
    const float4 er[4] = {*(const float4*)&eps[u4],
                          *(const float4*)&eps[256 + u4],
                          *(const float4*)&eps[512 + u4],
                          *(const float4*)&eps[768 + u4]};
#pragma unroll
    for (int r = 0; r < 4; ++r) {
      const float4 e = er[r];
      accA[r] = fmaf(vw.x, __builtin_amdgcn_rcpf(fmaf(e.x, ga.x, 1.0f)), accA[r]);
      accA[r] = fmaf(vw.y, __builtin_amdgcn_rcpf(fmaf(e.y, ga.y, 1.0f)), accA[r]);
      accA[r] = fmaf(vw.z, __builtin_amdgcn_rcpf(fmaf(e.z, ga.z, 1.0f)), accA[r]);
      accA[r] = fmaf(vw.w, __builtin_amdgcn_rcpf(fmaf(e.w, ga.w, 1.0f)), accA[r]);
      accB[r] = fmaf(vw.x, __builtin_amdgcn_rcpf(fmaf(e.x, gb.x, 1.0f)), accB[r]);
      accB[r] = fmaf(vw.y, __builtin_amdgcn_rcpf(fmaf(e.y, gb.y, 1.0f)), accB[r]);
      accB[r] = fmaf(vw.z, __builtin_amdgcn_rcpf(fmaf(e.z, gb.z, 1.0f)), accB[r]);
      accB[r] = fmaf(vw.w, __builtin_amdgcn_rcpf(fmaf(e.w, gb.w, 1.0f)), accB[r]);
    }
    ga = gan;
    gb = gbn;
  }

#pragma unroll
  for (int r = 0; r < 4; ++r) {
    comb[hq][r][p] = accA[r];
    comb[hq][r][p + 128] = accB[r];
  }
  __syncthreads();

  // ---- combine quarters + no-max softmax on threads 0..255 ----
  const int wid = tid >> 6, lane = tid & 63;
  float e[4];
  if (tid < 256) {
    const int t = tid;
#pragma unroll
    for (int r = 0; r < 4; ++r) {
      const float v = (comb[0][r][t] + comb[1][r][t]) +
                      (comb[2][r][t] + comb[3][r][t]);
      e[r] = __expf(-2.f * v);
      float s = e[r];
#pragma unroll
      for (int off = 32; off; off >>= 1) s += __shfl_xor(s, off);
      if (lane == 0) reds[r][wid] = s;
    }
  }
  __syncthreads();
  if (tid < 256) {
    const int t = tid;
#pragma unroll
    for (int r = 0; r < 4; ++r) {
      const float s = (reds[r][0] + reds[r][1]) + (reds[r][2] + reds[r][3]);
      const float pr = e[r] * __builtin_amdgcn_rcpf(s);
      attn[(((size_t)((b << 8) + s0 + r)) << 8) + t] = pr;
      att[r][t] = pr;
    }
  }
  __syncthreads();

  // ---- Phase 2: thread owns cols c4..c4+3, rows s0..s0+3, t-quarter tq.
  const int c4 = (tid & 127) << 2;
  const int tq = tid >> 7;  // 0..3
  const int tb = tq << 6;   // 64 t per quarter
  const float* __restrict__ encb = enc + ((size_t)b << 17) + c4;
  float4 acc0 = {0.f, 0.f, 0.f, 0.f};
  float4 acc1 = {0.f, 0.f, 0.f, 0.f};
  float4 acc2 = {0.f, 0.f, 0.f, 0.f};
  float4 acc3 = {0.f, 0.f, 0.f, 0.f};
#pragma unroll 2
  for (int t0 = tb; t0 < tb + 64; t0 += 4) {
    const float4 p0 = *(const float4*)&att[0][t0];
    const float4 p1 = *(const float4*)&att[1][t0];
    const float4 p2 = *(const float4*)&att[2][t0];
    const float4 p3 = *(const float4*)&att[3][t0];
    const float pv0[4] = {p0.x, p0.y, p0.z, p0.w};
    const float pv1[4] = {p1.x, p1.y, p1.z, p1.w};
    const float pv2[4] = {p2.x, p2.y, p2.z, p2.w};
    const float pv3[4] = {p3.x, p3.y, p3.z, p3.w};
#pragma unroll
    for (int i = 0; i < 4; ++i) {
      const float4 ev = *(const float4*)(encb + ((size_t)(t0 + i) << 9));
      acc0.x = fmaf(pv0[i], ev.x, acc0.x);
      acc0.y = fmaf(pv0[i], ev.y, acc0.y);
      acc0.z = fmaf(pv0[i], ev.z, acc0.z);
      acc0.w = fmaf(pv0[i], ev.w, acc0.w);
      acc1.x = fmaf(pv1[i], ev.x, acc1.x);
      acc1.y = fmaf(pv1[i], ev.y, acc1.y);
      acc1.z = fmaf(pv1[i], ev.z, acc1.z);
      acc1.w = fmaf(pv1[i], ev.w, acc1.w);
      acc2.x = fmaf(pv2[i], ev.x, acc2.x);
      acc2.y = fmaf(pv2[i], ev.y, acc2.y);
      acc2.z = fmaf(pv2[i], ev.z, acc2.z);
      acc2.w = fmaf(pv2[i], ev.w, acc2.w);
      acc3.x = fmaf(pv3[i], ev.x, acc3.x);
      acc3.y = fmaf(pv3[i], ev.y, acc3.y);
      acc3.z = fmaf(pv3[i], ev.z, acc3.z);
      acc3.w = fmaf(pv3[i], ev.w, acc3.w);
    }
  }
  if (tq != 0) {
    *(float4*)&ctx2[tq - 1][0][c4] = acc0;
    *(float4*)&ctx2[tq - 1][1][c4] = acc1;
    *(float4*)&ctx2[tq - 1][2][c4] = acc2;
    *(float4*)&ctx2[tq - 1][3][c4] = acc3;
  }
  __syncthreads();
  if (tq == 0) {
#pragma unroll
    for (int q = 0; q < 3; ++q) {
      const float4 q0 = *(const float4*)&ctx2[q][0][c4];
      const float4 q1 = *(const float4*)&ctx2[q][1][c4];
      const float4 q2 = *(const float4*)&ctx2[q][2][c4];
      const float4 q3 = *(const float4*)&ctx2[q][3][c4];
      acc0.x += q0.x; acc0.y += q0.y; acc0.z += q0.z; acc0.w += q0.w;
      acc1.x += q1.x; acc1.y += q1.y; acc1.z += q1.z; acc1.w += q1.w;
      acc2.x += q2.x; acc2.y += q2.y; acc2.z += q2.z; acc2.w += q2.w;
      acc3.x += q3.x; acc3.y += q3.y; acc3.z += q3.z; acc3.w += q3.w;
    }
    float* __restrict__ cb = ctx + (((size_t)((b << 8) + s0)) << 9) + c4;
    *(float4*)(cb + 0 * ED) = acc0;
    *(float4*)(cb + 1 * ED) = acc1;
    *(float4*)(cb + 2 * ED) = acc2;
    *(float4*)(cb + 3 * ED) = acc3;
  }
}

extern "C" void kernel_launch(void* const* d_in, const int* in_sizes, int n_in,
                              void* d_out, int out_size, void* d_ws, size_t ws_size,
                              hipStream_t stream) {
  const float* enc = (const float*)d_in[0];
  const float* dec = (const float*)d_in[1];
  const float* W1 = (const float*)d_in[2];
  const float* b1 = (const float*)d_in[3];
  const float* W2 = (const float*)d_in[4];
  const float* b2 = (const float*)d_in[5];
  const float* Vw = (const float*)d_in[6];
  // Vb cancels in softmax — unused.

  float* ctx = (float*)d_out;                          // (8,256,512)
  float* attn = (float*)d_out + (size_t)NB * TD * ED;  // (8,256,256)
  float* Epd = (float*)d_ws;                           // 512K floats
  float* EpeT2 = Epd + (size_t)NB * TD * DU;           // 512K floats

  proj_exp_kernel<<<dim3(512), dim3(512), 0, stream>>>(enc, dec, W1, b1, W2,
                                                       b2, Epd, EpeT2);
  score_ctx_kernel<<<dim3(512), dim3(512), 0, stream>>>(Epd, EpeT2, Vw, enc,
                                                        attn, ctx);
}